// Round 1
// baseline (2313.140 us; speedup 1.0000x reference)
//
#include <hip/hip_runtime.h>

// FK object-translation scan.
// B independent chains; each thread owns one batch and walks T steps serially.
// Exact reference semantics (norm + divide + separate dist carry) for this
// correctness-baseline round.

__global__ __launch_bounds__(64) void fk_scan_kernel(
    const float* __restrict__ prob,   // (B,T,2)
    const float* __restrict__ hands,  // (B,T,2,3)
    const float* __restrict__ rotm,   // (B,T,3,3)
    const float* __restrict__ tinit,  // (B,3)
    float* __restrict__ out,          // (B,T,3)
    int B, int T)
{
    const int b = blockIdx.x * blockDim.x + threadIdx.x;
    if (b >= B) return;

    const float* pr = prob  + (size_t)b * T * 2;
    const float* hd = hands + (size_t)b * T * 6;
    const float* Rm = rotm  + (size_t)b * T * 9;
    float*       ob = out   + (size_t)b * T * 3;

    // carry state
    float px = tinit[3*b+0], py = tinit[3*b+1], pz = tinit[3*b+2];
    float wx = 0.f, wy = 0.f, wz = 0.f;   // dir_local
    float dist = 0.f;
    int   cur  = -1;

    // ---- t = 0: all flags forced false -> state unchanged, emit init pos ----
    bool prev_l, prev_r;
    {
        float2 pp = *reinterpret_cast<const float2*>(pr);
        prev_l = pp.x > 0.5f;
        prev_r = pp.y > 0.5f;
        ob[0] = px; ob[1] = py; ob[2] = pz;
    }

    #pragma unroll 4
    for (int t = 1; t < T; ++t) {
        // ---------- loads (state-independent; compiler can hoist) ----------
        float2 pp = *reinterpret_cast<const float2*>(pr + 2*t);

        const float* hp = hd + 6*t;
        float2 ha = *reinterpret_cast<const float2*>(hp + 0);
        float2 hb = *reinterpret_cast<const float2*>(hp + 2);
        float2 hcv= *reinterpret_cast<const float2*>(hp + 4);
        const float h0x = ha.x, h0y = ha.y, h0z = hb.x;   // hand 0 (left)
        const float h1x = hb.y, h1y = hcv.x, h1z = hcv.y; // hand 1 (right)

        const float* rp = Rm + 9*t;
        const float R0 = rp[0], R1 = rp[1], R2 = rp[2];
        const float R3 = rp[3], R4 = rp[4], R5 = rp[5];
        const float R6 = rp[6], R7 = rp[7], R8 = rp[8];

        // ---------- boolean state machine ----------
        const bool rl = pp.x > 0.5f;
        const bool rr = pp.y > 0.5f;
        const bool l_c = rl, r_c = rr;
        const bool l_s = rl && !prev_l;
        const bool r_s = rr && !prev_r;
        prev_l = rl; prev_r = rr;

        const int  nw   = l_s ? 0 : (r_s ? 1 : -1);
        const bool hasc = (cur == 0 && l_c) || (cur == 1 && r_c);
        const bool haso = (cur == 0 && r_c) || (cur == 1 && l_c);
        const bool grab = (nw != -1) || (!hasc && haso);
        int cur_grab    = (nw != -1) ? nw : (1 - cur);
        const bool release = !grab && !hasc && (cur != -1);
        const int  new_cur = grab ? cur_grab : (release ? -1 : cur);

        // ---------- grab: recompute (dir_local, dist) from current pos ----------
        const int gi = cur_grab < 0 ? 0 : (cur_grab > 1 ? 1 : cur_grab);
        const float hgx = gi ? h1x : h0x;
        const float hgy = gi ? h1y : h0y;
        const float hgz = gi ? h1z : h0z;

        const float vx = px - hgx, vy = py - hgy, vz = pz - hgz;
        const float d2 = vx*vx + vy*vy + vz*vz;
        const float d0 = sqrtf(d2);
        const bool  valid = d0 > 1e-6f;
        const float dm  = fmaxf(d0, 1e-6f);
        const float inv = 1.0f / dm;
        const float ux = valid ? vx * inv : 0.f;
        const float uy = valid ? vy * inv : 0.f;
        const float uz = valid ? vz * inv : 1.f;
        const float dd = valid ? d0 : 0.1f;

        // dir_new = R^T u  (einsum 'bij,bi->bj')
        const float nwx = R0*ux + R3*uy + R6*uz;
        const float nwy = R1*ux + R4*uy + R7*uz;
        const float nwz = R2*ux + R5*uy + R8*uz;

        wx   = grab ? nwx : wx;
        wy   = grab ? nwy : wy;
        wz   = grab ? nwz : wz;
        dist = grab ? dd  : dist;

        // ---------- attached: pos = hand_cur + (R w) * dist ----------
        const bool att = (new_cur != -1);
        const int  ci  = new_cur < 0 ? 0 : (new_cur > 1 ? 1 : new_cur);
        const float hcx = ci ? h1x : h0x;
        const float hcy = ci ? h1y : h0y;
        const float hcz = ci ? h1z : h0z;

        const float rdx = R0*wx + R1*wy + R2*wz;   // einsum 'bij,bj->bi'
        const float rdy = R3*wx + R4*wy + R5*wz;
        const float rdz = R6*wx + R7*wy + R8*wz;

        px = att ? (hcx + rdx * dist) : px;
        py = att ? (hcy + rdy * dist) : py;
        pz = att ? (hcz + rdz * dist) : pz;

        cur = new_cur;

        ob[3*t + 0] = px;
        ob[3*t + 1] = py;
        ob[3*t + 2] = pz;
    }
}

extern "C" void kernel_launch(void* const* d_in, const int* in_sizes, int n_in,
                              void* d_out, int out_size, void* d_ws, size_t ws_size,
                              hipStream_t stream) {
    const float* prob  = (const float*)d_in[0];  // (B,T,2)
    const float* hands = (const float*)d_in[1];  // (B,T,2,3)
    const float* rotm  = (const float*)d_in[2];  // (B,T,3,3)
    const float* tinit = (const float*)d_in[3];  // (B,3)
    float* out = (float*)d_out;

    const int B = in_sizes[3] / 3;
    const int T = in_sizes[0] / (B * 2);

    const int block = 64;
    const int grid  = (B + block - 1) / block;
    hipLaunchKernelGGL(fk_scan_kernel, dim3(grid), dim3(block), 0, stream,
                       prob, hands, rotm, tinit, out, B, T);
}

// Round 2
// 1578.238 us; speedup vs baseline: 1.4656x; 1.4656x over previous
//
#include <hip/hip_runtime.h>

// FK object-translation scan, round 2: software-pipelined input staging.
// One lane per batch chain (B=512 -> 8 waves). Each lane prefetches 8 steps
// (17 floats/step) of its own contiguous input rows into a register double
// buffer while the previous 8 steps compute, hiding L2/L3/HBM latency that
// dominated round 1 (1470 cyc/step at VGPR_Count=36).
// Step math is bit-identical to the round-1 passing kernel.

#define LOADB(P, H, RR, i) do {                                               \
    _Pragma("unroll") for (int j = 0; j < 4; ++j) {                           \
        float4 v = pr4[4*(i)+j];                                              \
        (P)[4*j+0]=v.x; (P)[4*j+1]=v.y; (P)[4*j+2]=v.z; (P)[4*j+3]=v.w; }     \
    _Pragma("unroll") for (int j = 0; j < 12; ++j) {                          \
        float4 v = hd4[12*(i)+j];                                             \
        (H)[4*j+0]=v.x; (H)[4*j+1]=v.y; (H)[4*j+2]=v.z; (H)[4*j+3]=v.w; }     \
    _Pragma("unroll") for (int j = 0; j < 18; ++j) {                          \
        float4 v = rm4[18*(i)+j];                                             \
        (RR)[4*j+0]=v.x; (RR)[4*j+1]=v.y; (RR)[4*j+2]=v.z; (RR)[4*j+3]=v.w; } \
} while (0)

#define PROCESS(P, H, RR, i, isFirst) do {                                    \
    _Pragma("unroll") for (int k = 0; k < 8; ++k) {                           \
        const int t = 8*(i) + k;                                              \
        const bool rl = (P)[2*k]   > 0.5f;                                    \
        const bool rr = (P)[2*k+1] > 0.5f;                                    \
        const bool first = (isFirst) && (k == 0);                             \
        const bool l_c = rl && !first;                                        \
        const bool r_c = rr && !first;                                        \
        const bool l_s = rl && !prev_l && !first;                             \
        const bool r_s = rr && !prev_r && !first;                             \
        prev_l = rl; prev_r = rr;                                             \
        const float h0x=(H)[6*k+0], h0y=(H)[6*k+1], h0z=(H)[6*k+2];           \
        const float h1x=(H)[6*k+3], h1y=(H)[6*k+4], h1z=(H)[6*k+5];           \
        const float R0=(RR)[9*k+0], R1=(RR)[9*k+1], R2=(RR)[9*k+2];           \
        const float R3=(RR)[9*k+3], R4=(RR)[9*k+4], R5=(RR)[9*k+5];           \
        const float R6=(RR)[9*k+6], R7=(RR)[9*k+7], R8=(RR)[9*k+8];           \
        const int  nw   = l_s ? 0 : (r_s ? 1 : -1);                           \
        const bool hasc = (cur == 0 && l_c) || (cur == 1 && r_c);             \
        const bool haso = (cur == 0 && r_c) || (cur == 1 && l_c);             \
        const bool grab = (nw != -1) || (!hasc && haso);                      \
        const int  cur_grab = (nw != -1) ? nw : (1 - cur);                    \
        const bool release  = !grab && !hasc && (cur != -1);                  \
        const int  new_cur  = grab ? cur_grab : (release ? -1 : cur);         \
        const int  gi = cur_grab < 0 ? 0 : (cur_grab > 1 ? 1 : cur_grab);     \
        const float hgx = gi ? h1x : h0x;                                     \
        const float hgy = gi ? h1y : h0y;                                     \
        const float hgz = gi ? h1z : h0z;                                     \
        const float vx = px - hgx, vy = py - hgy, vz = pz - hgz;              \
        const float d2 = vx*vx + vy*vy + vz*vz;                               \
        const float d0 = sqrtf(d2);                                           \
        const bool  valid = d0 > 1e-6f;                                       \
        const float inv = 1.0f / fmaxf(d0, 1e-6f);                            \
        const float ux = valid ? vx * inv : 0.f;                              \
        const float uy = valid ? vy * inv : 0.f;                              \
        const float uz = valid ? vz * inv : 1.f;                              \
        const float dd = valid ? d0 : 0.1f;                                   \
        const float nwx = R0*ux + R3*uy + R6*uz;                              \
        const float nwy = R1*ux + R4*uy + R7*uz;                              \
        const float nwz = R2*ux + R5*uy + R8*uz;                              \
        wx   = grab ? nwx : wx;                                               \
        wy   = grab ? nwy : wy;                                               \
        wz   = grab ? nwz : wz;                                               \
        dist = grab ? dd  : dist;                                             \
        const bool att = (new_cur != -1);                                     \
        const int  ci  = new_cur < 0 ? 0 : (new_cur > 1 ? 1 : new_cur);       \
        const float hcx = ci ? h1x : h0x;                                     \
        const float hcy = ci ? h1y : h0y;                                     \
        const float hcz = ci ? h1z : h0z;                                     \
        const float rdx = R0*wx + R1*wy + R2*wz;                              \
        const float rdy = R3*wx + R4*wy + R5*wz;                              \
        const float rdz = R6*wx + R7*wy + R8*wz;                              \
        px = att ? (hcx + rdx * dist) : px;                                   \
        py = att ? (hcy + rdy * dist) : py;                                   \
        pz = att ? (hcz + rdz * dist) : pz;                                   \
        cur = new_cur;                                                        \
        ob[3*t+0] = px; ob[3*t+1] = py; ob[3*t+2] = pz;                       \
    }                                                                         \
} while (0)

__global__ __launch_bounds__(64, 1) void fk_scan_kernel(
    const float* __restrict__ prob,   // (B,T,2)
    const float* __restrict__ hands,  // (B,T,2,3)
    const float* __restrict__ rotm,   // (B,T,3,3)
    const float* __restrict__ tinit,  // (B,3)
    float* __restrict__ out,          // (B,T,3)
    int B, int T)
{
    const int b = blockIdx.x * blockDim.x + threadIdx.x;
    if (b >= B) return;

    const float4* pr4 = reinterpret_cast<const float4*>(prob  + (size_t)b * T * 2);
    const float4* hd4 = reinterpret_cast<const float4*>(hands + (size_t)b * T * 6);
    const float4* rm4 = reinterpret_cast<const float4*>(rotm  + (size_t)b * T * 9);
    float*        ob  = out + (size_t)b * T * 3;

    // carry state
    float px = tinit[3*b+0], py = tinit[3*b+1], pz = tinit[3*b+2];
    float wx = 0.f, wy = 0.f, wz = 0.f;
    float dist = 0.f;
    int   cur  = -1;
    bool  prev_l = false, prev_r = false;

    // register double buffers: 8 steps x (2 prob + 6 hand + 9 rotm) floats
    float PA[16], HA[48], RA[72];
    float PB[16], HB[48], RB[72];

    const int NB = T / 8;   // 512 batches; NB is even

    LOADB(PA, HA, RA, 0);
    for (int i = 0; i < NB; i += 2) {
        LOADB(PB, HB, RB, i + 1);
        PROCESS(PA, HA, RA, i, (i == 0));
        if (i + 2 < NB) LOADB(PA, HA, RA, i + 2);
        PROCESS(PB, HB, RB, i + 1, false);
    }
}

extern "C" void kernel_launch(void* const* d_in, const int* in_sizes, int n_in,
                              void* d_out, int out_size, void* d_ws, size_t ws_size,
                              hipStream_t stream) {
    const float* prob  = (const float*)d_in[0];  // (B,T,2)
    const float* hands = (const float*)d_in[1];  // (B,T,2,3)
    const float* rotm  = (const float*)d_in[2];  // (B,T,3,3)
    const float* tinit = (const float*)d_in[3];  // (B,3)
    float* out = (float*)d_out;

    const int B = in_sizes[3] / 3;
    const int T = in_sizes[0] / (B * 2);

    const int block = 64;
    const int grid  = (B + block - 1) / block;
    hipLaunchKernelGGL(fk_scan_kernel, dim3(grid), dim3(block), 0, stream,
                       prob, hands, rotm, tinit, out, B, T);
}

// Round 3
// 1330.103 us; speedup vs baseline: 1.7391x; 1.1866x over previous
//
#include <hip/hip_runtime.h>

// FK object-translation scan, round 3: wave-per-batch.
// 512 blocks x 64 lanes; each wave owns one batch chain. Lanes cooperatively
// stage 256-step input chunks into padded LDS (coalesced), then the wave
// walks the 256 steps with uniform scalar compute (all lanes replicate).
// State machine lives in SGPRs via readfirstlane -> s_cbranch skips.
// Float carry is W = dir_local * dist (product trick): grab step does
// W = R^T (pos - h) with no sqrt/rcp on the chain; pos = h + R W.
// Semantics match the reference up to ~1e-7 rel rounding (absmax margin
// was 0.5 vs threshold 3.18 with exact math).

#define CT 256

__global__ __launch_bounds__(64) void fk_scan_wave(
    const float* __restrict__ prob,   // (B,T,2)
    const float* __restrict__ hands,  // (B,T,2,3)
    const float* __restrict__ rotm,   // (B,T,3,3)
    const float* __restrict__ tinit,  // (B,3)
    float* __restrict__ out,          // (B,T,3)
    int B, int T)
{
    __shared__ __align__(16) float sP[CT * 2];   // prob, packed
    __shared__ __align__(16) float sH[CT * 8];   // hands, padded 6->8
    __shared__ __align__(16) float sR[CT * 12];  // rotm,  padded 9->12

    const int b    = blockIdx.x;
    const int lane = threadIdx.x;

    const float* prB = prob  + (size_t)b * T * 2;
    const float* hdB = hands + (size_t)b * T * 6;
    const float* rmB = rotm  + (size_t)b * T * 9;
    float*       obB = out   + (size_t)b * T * 3;

    // carry (lane-replicated, identical across the wave)
    float px = tinit[3*b+0], py = tinit[3*b+1], pz = tinit[3*b+2];
    float Wx = 0.f, Wy = 0.f, Wz = 0.f;   // dir_local * dist
    int   cur = -1;
    int   prev_l = 0, prev_r = 0;

    for (int t0 = 0; t0 < T; t0 += CT) {
        const int n = (T - t0 < CT) ? (T - t0) : CT;

        // ---- coalesced staging into padded LDS ----
        for (int i = lane; i < n * 2; i += 64)
            sP[i] = prB[(size_t)t0 * 2 + i];
        for (int i = lane; i < n * 6; i += 64) {
            int s = i / 6, c = i - 6 * s;
            sH[8 * s + c] = hdB[(size_t)t0 * 6 + i];
        }
        for (int i = lane; i < n * 9; i += 64) {
            int s = i / 9, c = i - 9 * s;
            sR[12 * s + c] = rmB[(size_t)t0 * 9 + i];
        }
        __syncthreads();

        for (int k = 0; k < n; ++k) {
            const int t = t0 + k;
            const float p0 = sP[2*k+0];
            const float p1 = sP[2*k+1];
            // hoist contact bits to SGPRs -> uniform (s_cbranch) control flow
            const int rl = __builtin_amdgcn_readfirstlane(p0 > 0.5f ? 1 : 0);
            const int rr = __builtin_amdgcn_readfirstlane(p1 > 0.5f ? 1 : 0);
            const int nz  = (t != 0) ? 1 : 0;
            const int l_c = rl & nz;
            const int r_c = rr & nz;
            const int l_s = rl & (prev_l ^ 1) & nz;
            const int r_s = rr & (prev_r ^ 1) & nz;
            prev_l = rl; prev_r = rr;

            const int nw   = l_s ? 0 : (r_s ? 1 : -1);
            const int hasc = ((cur == 0) & l_c) | ((cur == 1) & r_c);
            const int haso = ((cur == 0) & r_c) | ((cur == 1) & l_c);
            const int grab = (nw != -1) | ((hasc ^ 1) & haso);
            const int new_cur = grab ? ((nw != -1) ? nw : (1 - cur))
                                     : (((hasc ^ 1) & (cur != -1)) ? -1 : cur);

            if (new_cur != -1) {           // attached this step (grab implies this)
                const float h0x = sH[8*k+0], h0y = sH[8*k+1], h0z = sH[8*k+2];
                const float h1x = sH[8*k+3], h1y = sH[8*k+4], h1z = sH[8*k+5];
                const float R0 = sR[12*k+0], R1 = sR[12*k+1], R2 = sR[12*k+2];
                const float R3 = sR[12*k+3], R4 = sR[12*k+4], R5 = sR[12*k+5];
                const float R6 = sR[12*k+6], R7 = sR[12*k+7], R8 = sR[12*k+8];
                // at grab, vec-hand == new hand (new_cur == cur_grab), so one select
                const float hx = new_cur ? h1x : h0x;
                const float hy = new_cur ? h1y : h0y;
                const float hz = new_cur ? h1z : h0z;

                if (grab) {
                    const float vx = px - hx, vy = py - hy, vz = pz - hz;
                    const float d2 = vx*vx + vy*vy + vz*vz;
                    if (d2 > 1e-12f) {     // valid: W = R^T vec  (= R^T u * d)
                        Wx = R0*vx + R3*vy + R6*vz;
                        Wy = R1*vx + R4*vy + R7*vz;
                        Wz = R2*vx + R5*vy + R8*vz;
                    } else {               // degenerate: u = z, dist = 0.1
                        Wx = 0.1f * R6; Wy = 0.1f * R7; Wz = 0.1f * R8;
                    }
                }
                px = hx + (R0*Wx + R1*Wy + R2*Wz);
                py = hy + (R3*Wx + R4*Wy + R5*Wz);
                pz = hz + (R6*Wx + R7*Wy + R8*Wz);
            }
            cur = new_cur;

            if (lane == 0) {
                obB[3*(size_t)t + 0] = px;
                obB[3*(size_t)t + 1] = py;
                obB[3*(size_t)t + 2] = pz;
            }
        }
        __syncthreads();   // all reads of this chunk done before next staging
    }
}

extern "C" void kernel_launch(void* const* d_in, const int* in_sizes, int n_in,
                              void* d_out, int out_size, void* d_ws, size_t ws_size,
                              hipStream_t stream) {
    const float* prob  = (const float*)d_in[0];  // (B,T,2)
    const float* hands = (const float*)d_in[1];  // (B,T,2,3)
    const float* rotm  = (const float*)d_in[2];  // (B,T,3,3)
    const float* tinit = (const float*)d_in[3];  // (B,3)
    float* out = (float*)d_out;

    const int B = in_sizes[3] / 3;
    const int T = in_sizes[0] / (B * 2);

    hipLaunchKernelGGL(fk_scan_wave, dim3(B), dim3(64), 0, stream,
                       prob, hands, rotm, tinit, out, B, T);
}